// Round 6
// baseline (929.533 us; speedup 1.0000x reference)
//
#include <hip/hip_runtime.h>

#define B_ 2048
#define F_ 16384
#define D_ 512
#define O_ 4096

typedef __attribute__((ext_vector_type(8))) short bf16x8;
typedef __attribute__((ext_vector_type(4))) float f32x4;

__device__ inline unsigned short f2bf(float f) {
    unsigned u = __float_as_uint(f);
    u += 0x7FFFu + ((u >> 16) & 1u);   // RNE
    return (unsigned short)(u >> 16);
}

__device__ inline void glds16(const void* g, void* l) {
    __builtin_amdgcn_global_load_lds((const __attribute__((address_space(1))) void*)g,
                                     (__attribute__((address_space(3))) void*)l, 16, 0, 0);
}

// ---------------- fp32 -> bf16 bulk convert ----------------
__global__ void cvt_bf16_kernel(const float* __restrict__ s, unsigned short* __restrict__ d, int n4) {
    int stride = gridDim.x * blockDim.x;
    for (int i = blockIdx.x * blockDim.x + threadIdx.x; i < n4; i += stride) {
        float4 v = ((const float4*)s)[i];
        ushort4 o;
        o.x = f2bf(v.x); o.y = f2bf(v.y); o.z = f2bf(v.z); o.w = f2bf(v.w);
        ((ushort4*)d)[i] = o;
    }
}

// ---------------- per-row top-20 (exact, JAX tie-break) + bf16 emit ----------------
// key = (float_bits(v) << 32) | ~idx  : larger key = larger value, tie -> smaller idx.
__global__ __launch_bounds__(256) void topk_kernel(const float* __restrict__ sae,
        float* __restrict__ tv, int* __restrict__ ti, unsigned short* __restrict__ sae_bf) {
    __shared__ unsigned long long keys[256 * 20];  // 40 KB
    __shared__ unsigned long long tmp[128 * 20];   // 20 KB
    int tid = threadIdx.x;
    int row = blockIdx.x;
    const float* p = sae + (size_t)row * F_;
    unsigned short* pb = sae_bf + (size_t)row * F_;

    unsigned long long loc[20];
#pragma unroll
    for (int m = 0; m < 20; ++m) loc[m] = 0ull;

#pragma unroll 2
    for (int it = 0; it < F_ / 256; ++it) {
        int i = tid + (it << 8);
        float v = p[i];
        pb[i] = f2bf(v);
        unsigned long long key =
            ((unsigned long long)__float_as_uint(v) << 32) | (unsigned)(~i);
        if (key > loc[19]) {
            loc[19] = key;
#pragma unroll
            for (int j = 19; j > 0; --j) {       // bubble new key up; static indexing only
                unsigned long long a = loc[j - 1], b = loc[j];
                loc[j - 1] = a > b ? a : b;
                loc[j]     = a > b ? b : a;
            }
        }
    }
#pragma unroll
    for (int m = 0; m < 20; ++m) keys[tid * 20 + m] = loc[m];
    __syncthreads();

    for (int step = 1; step < 256; step <<= 1) {
        if ((tid & (2 * step - 1)) == 0) {
            unsigned long long* a = &keys[tid * 20];
            const unsigned long long* b = &keys[(tid + step) * 20];
            unsigned long long* o = &tmp[(tid >> 1) * 20];
            int i = 0, j = 0;
            for (int m = 0; m < 20; ++m) {
                unsigned long long va = a[i], vb = b[j];
                if (va >= vb) { o[m] = va; ++i; } else { o[m] = vb; ++j; }
            }
            for (int m = 0; m < 20; ++m) a[m] = o[m];
        }
        __syncthreads();
    }
    if (tid < 20) {
        unsigned long long k = keys[tid];
        tv[row * 20 + tid] = __uint_as_float((unsigned)(k >> 32));
        ti[row * 20 + tid] = (int)(~(unsigned)k);
    }
}

// ---------------- bi-interaction pooling from sparse top-k ----------------
__global__ __launch_bounds__(256) void bi_kernel(const int* __restrict__ ti,
        const float* __restrict__ tv, const float* __restrict__ emb, float* __restrict__ bi) {
    __shared__ int   si[20];
    __shared__ float sv[20];
    int tid = threadIdx.x, row = blockIdx.x;
    if (tid < 20) { si[tid] = ti[row * 20 + tid]; sv[tid] = tv[row * 20 + tid]; }
    __syncthreads();
    float s0 = 0.f, q0 = 0.f, s1 = 0.f, q1 = 0.f;
    int d0 = tid, d1 = tid + 256;
#pragma unroll
    for (int k = 0; k < 20; ++k) {
        float v = sv[k];
        const float* e = emb + (size_t)si[k] * D_;
        float e0 = e[d0], e1 = e[d1];
        s0 += v * e0; q0 += v * v * e0 * e0;
        s1 += v * e1; q1 += v * v * e1 * e1;
    }
    bi[(size_t)row * D_ + d0] = 0.5f * (s0 * s0 - q0);
    bi[(size_t)row * D_ + d1] = 0.5f * (s1 * s1 - q1);
}

// ---------------- column mean/var -> scale/shift (training BN) ----------------
__global__ __launch_bounds__(256) void colstats_kernel(const float* __restrict__ X,
        const float* __restrict__ gamma, const float* __restrict__ beta,
        float* __restrict__ scale, float* __restrict__ shift, int M, int N) {
    __shared__ float ss[256], qq[256];
    int col = blockIdx.x, tid = threadIdx.x;
    float s = 0.f, q = 0.f;
    for (int r = tid; r < M; r += 256) {
        float x = X[(size_t)r * N + col];
        s += x; q += x * x;
    }
    ss[tid] = s; qq[tid] = q;
    __syncthreads();
    for (int o = 128; o > 0; o >>= 1) {
        if (tid < o) { ss[tid] += ss[tid + o]; qq[tid] += qq[tid + o]; }
        __syncthreads();
    }
    if (tid == 0) {
        float mean = ss[0] / M;
        float var = qq[0] / M - mean * mean;
        float sc = gamma[col] * rsqrtf(var + 1e-5f);
        scale[col] = sc;
        shift[col] = beta[col] - mean * sc;
    }
}

// ---------------- apply BN (+ optional relu), emit bf16 ----------------
__global__ void bn_apply_kernel(const float* __restrict__ X, const float* __restrict__ scale,
        const float* __restrict__ shift, unsigned short* __restrict__ Y,
        int n4, int colmask4, int relu) {
    int stride = gridDim.x * blockDim.x;
    for (int i = blockIdx.x * blockDim.x + threadIdx.x; i < n4; i += stride) {
        float4 x = ((const float4*)X)[i];
        int c = (i & colmask4) * 4;
        float4 sc = *(const float4*)(scale + c);
        float4 sh = *(const float4*)(shift + c);
        float y0 = x.x * sc.x + sh.x;
        float y1 = x.y * sc.y + sh.y;
        float y2 = x.z * sc.z + sh.z;
        float y3 = x.w * sc.w + sh.w;
        if (relu) {
            y0 = fmaxf(y0, 0.f); y1 = fmaxf(y1, 0.f);
            y2 = fmaxf(y2, 0.f); y3 = fmaxf(y3, 0.f);
        }
        ushort4 o;
        o.x = f2bf(y0); o.y = f2bf(y1); o.z = f2bf(y2); o.w = f2bf(y3);
        ((ushort4*)Y)[i] = o;
    }
}

// ---------------- bf16 GEMM, 4-wave, swizzled LDS, depth-2 counted-vmcnt pipeline ----
// out[M,N] = A[M,K] @ W[N,K]^T + bias[N].  128x128 tile, BK=32, 256 threads = 4 waves
// (2x2), per-wave 64x64 output (16 MFMA per 8 ds_read_b128 per K-step).
// LDS swizzle (both-sides, rule #21): physical 16B-chunk = logical ^ ((row>>1)&3).
//   write side: global source chunk pre-swizzled (stays inside the 64B row);
//   read side: chunk = lhi ^ ((l15>>1)&3)  -> 16-lane chunk-start banks hit
//   {0,4,...,28} x2 lanes = 2-way = conflict-free (m136).
// Counted vmcnt keeps 8 prefetch loads in flight across barriers (T4).
// FUSE: additionally write out0 = gb[col] + lin[idx] + (acc+bias).
template <bool FUSE>
__global__ __launch_bounds__(256) void gemm4w_kernel(const unsigned short* __restrict__ A,
        const unsigned short* __restrict__ W, const float* __restrict__ bias,
        float* __restrict__ out, const float* __restrict__ lin,
        const float* __restrict__ gb, float* __restrict__ out0,
        int M, int N, int K) {
    __shared__ short As[3 * 4096];  // 3 buffers x 8 KB
    __shared__ short Bs[3 * 4096];
    int tid = threadIdx.x;
    int lane = tid & 63, w = tid >> 6;      // 4 waves
    int wr = w >> 1, wc = w & 1;            // 2 x 2
    int l15 = lane & 15, lhi = lane >> 4;
    int xk = (l15 >> 1) & 3;                // read-side swizzle key

    // XCD-aware swizzle (all call sites have nwg % 8 == 0)
    int nwg = gridDim.x * gridDim.y;
    int bid = blockIdx.y * gridDim.x + blockIdx.x;
    int swz = (bid & 7) * (nwg >> 3) + (bid >> 3);
    int bx = swz % gridDim.x, by = swz / gridDim.x;
    int bm = by * 128, bn = bx * 128;

    int rA = tid >> 2;                      // 0..63
    int kp = tid & 3;                       // logical 16B chunk
    int kps = kp ^ ((rA >> 1) & 3);         // pre-swizzled source chunk (in [0,4))
    const unsigned short* gA0 = A + (size_t)(bm + rA) * K + kps * 8;
    const unsigned short* gA1 = A + (size_t)(bm + rA + 64) * K + kps * 8;  // (rA+64)>>1 & 3 == rA>>1 & 3
    const unsigned short* gB0 = W + (size_t)(bn + rA) * K + kps * 8;
    const unsigned short* gB1 = W + (size_t)(bn + rA + 64) * K + kps * 8;

    f32x4 acc[4][4];
#pragma unroll
    for (int i = 0; i < 4; ++i)
#pragma unroll
        for (int j = 0; j < 4; ++j) { f32x4 z = {0.f, 0.f, 0.f, 0.f}; acc[i][j] = z; }

    auto STAGE = [&](int t, int buf) {
        int k0 = t << 5;
        char* la = (char*)As + buf * 8192 + w * 1024;  // wave-uniform base; lane l at +l*16
        char* lb = (char*)Bs + buf * 8192 + w * 1024;
        glds16(gA0 + k0, la);
        glds16(gA1 + k0, la + 4096);
        glds16(gB0 + k0, lb);
        glds16(gB1 + k0, lb + 4096);
    };
    auto COMP = [&](int buf) {
        const short* Ab = As + buf * 4096;
        const short* Bb = Bs + buf * 4096;
        bf16x8 af[4], bv[4];
#pragma unroll
        for (int mi = 0; mi < 4; ++mi)
            af[mi] = *(const bf16x8*)&Ab[(wr * 64 + mi * 16 + l15) * 32 + ((lhi ^ xk) << 3)];
#pragma unroll
        for (int ni = 0; ni < 4; ++ni)
            bv[ni] = *(const bf16x8*)&Bb[(wc * 64 + ni * 16 + l15) * 32 + ((lhi ^ xk) << 3)];
#pragma unroll
        for (int mi = 0; mi < 4; ++mi)
#pragma unroll
            for (int ni = 0; ni < 4; ++ni)
                acc[mi][ni] = __builtin_amdgcn_mfma_f32_16x16x32_bf16(af[mi], bv[ni], acc[mi][ni], 0, 0, 0);
    };

    int NT = K >> 5;  // >= 16 at all call sites
    STAGE(0, 0);
    STAGE(1, 1);
    int buf = 0;
    for (int t = 0; t < NT - 2; ++t) {
        int nb = buf + 2; if (nb >= 3) nb -= 3;
        STAGE(t + 2, nb);
        asm volatile("s_waitcnt vmcnt(8)" ::: "memory");   // tile t landed; t+1,t+2 in flight
        __builtin_amdgcn_sched_barrier(0);
        __builtin_amdgcn_s_barrier();
        __builtin_amdgcn_sched_barrier(0);
        COMP(buf);
        asm volatile("s_waitcnt lgkmcnt(0)" ::: "memory"); // my ds_reads landed in regs
        __builtin_amdgcn_sched_barrier(0);
        __builtin_amdgcn_s_barrier();                      // safe to overwrite buf next iter
        __builtin_amdgcn_sched_barrier(0);
        ++buf; if (buf >= 3) buf = 0;
    }
    // t = NT-2: only tile NT-1's loads (4) still in flight
    asm volatile("s_waitcnt vmcnt(4)" ::: "memory");
    __builtin_amdgcn_sched_barrier(0);
    __builtin_amdgcn_s_barrier();
    __builtin_amdgcn_sched_barrier(0);
    COMP(buf);
    asm volatile("s_waitcnt lgkmcnt(0)" ::: "memory");
    __builtin_amdgcn_sched_barrier(0);
    __builtin_amdgcn_s_barrier();
    __builtin_amdgcn_sched_barrier(0);
    ++buf; if (buf >= 3) buf = 0;
    // t = NT-1: drain
    asm volatile("s_waitcnt vmcnt(0)" ::: "memory");
    __builtin_amdgcn_sched_barrier(0);
    __builtin_amdgcn_s_barrier();
    __builtin_amdgcn_sched_barrier(0);
    COMP(buf);

#pragma unroll
    for (int mi = 0; mi < 4; ++mi)
#pragma unroll
        for (int ni = 0; ni < 4; ++ni) {
            int col = bn + wc * 64 + ni * 16 + l15;
            float bb = bias[col];
            float gbv = FUSE ? gb[col] : 0.f;
            int row0 = bm + wr * 64 + mi * 16 + lhi * 4;
#pragma unroll
            for (int r = 0; r < 4; ++r) {
                size_t idx = (size_t)(row0 + r) * N + col;
                float v = acc[mi][ni][r] + bb;
                out[idx] = v;
                if (FUSE) out0[idx] = gbv + lin[idx] + v;
            }
        }
}

extern "C" void kernel_launch(void* const* d_in, const int* in_sizes, int n_in,
                              void* d_out, int out_size, void* d_ws, size_t ws_size,
                              hipStream_t stream) {
    const float* sae  = (const float*)d_in[0];
    const float* emb  = (const float*)d_in[1];
    const float* lin_w = (const float*)d_in[2];
    const float* lin_b = (const float*)d_in[3];
    const float* gbias = (const float*)d_in[4];
    const float* bn1g = (const float*)d_in[5];
    const float* bn1b = (const float*)d_in[6];
    const float* w1   = (const float*)d_in[7];
    const float* b1   = (const float*)d_in[8];
    const float* bn2g = (const float*)d_in[9];
    const float* bn2b = (const float*)d_in[10];
    const float* w2   = (const float*)d_in[11];
    const float* b2   = (const float*)d_in[12];
    float* out = (float*)d_out;
    const size_t BO = (size_t)B_ * O_;

    char* ws = (char*)d_ws;
    auto alloc = [&](size_t bytes) -> char* {
        char* p = ws;
        ws += (bytes + 255) & ~(size_t)255;
        return p;
    };
    unsigned short* sae_bf  = (unsigned short*)alloc((size_t)B_ * F_ * 2);  // 64 MB
    unsigned short* linw_bf = (unsigned short*)alloc((size_t)O_ * F_ * 2);  // 128 MB
    unsigned short* w1_bf   = (unsigned short*)alloc((size_t)D_ * D_ * 2);
    unsigned short* w2_bf   = (unsigned short*)alloc((size_t)O_ * D_ * 2);
    unsigned short* a1_bf   = (unsigned short*)alloc((size_t)B_ * D_ * 2);
    unsigned short* h2_bf   = (unsigned short*)alloc((size_t)B_ * D_ * 2);
    float* tv = (float*)alloc((size_t)B_ * 20 * 4);
    int*   ti = (int*)alloc((size_t)B_ * 20 * 4);
    float* bi = (float*)alloc((size_t)B_ * D_ * 4);
    float* h1 = (float*)alloc((size_t)B_ * D_ * 4);
    float* sc1 = (float*)alloc(D_ * 4);
    float* sh1 = (float*)alloc(D_ * 4);
    float* sc2 = (float*)alloc(D_ * 4);
    float* sh2 = (float*)alloc(D_ * 4);

    // weight conversions (independent of data path)
    cvt_bf16_kernel<<<2048, 256, 0, stream>>>(lin_w, linw_bf, (int)((size_t)O_ * F_ / 4));
    cvt_bf16_kernel<<<256, 256, 0, stream>>>(w1, w1_bf, D_ * D_ / 4);
    cvt_bf16_kernel<<<1024, 256, 0, stream>>>(w2, w2_bf, O_ * D_ / 4);

    // top-k + sae bf16 emit
    topk_kernel<<<B_, 256, 0, stream>>>(sae, tv, ti, sae_bf);

    // bi-interaction pooling
    bi_kernel<<<B_, 256, 0, stream>>>(ti, tv, emb, bi);

    // BN1 -> bf16, GEMM1
    colstats_kernel<<<D_, 256, 0, stream>>>(bi, bn1g, bn1b, sc1, sh1, B_, D_);
    bn_apply_kernel<<<1024, 256, 0, stream>>>(bi, sc1, sh1, a1_bf, B_ * D_ / 4, D_ / 4 - 1, 0);
    gemm4w_kernel<false><<<dim3(D_ / 128, B_ / 128), 256, 0, stream>>>(
        a1_bf, w1_bf, b1, h1, nullptr, nullptr, nullptr, B_, D_, D_);

    // BN2 + relu -> bf16
    colstats_kernel<<<D_, 256, 0, stream>>>(h1, bn2g, bn2b, sc2, sh2, B_, D_);
    bn_apply_kernel<<<1024, 256, 0, stream>>>(h1, sc2, sh2, h2_bf, B_ * D_ / 4, D_ / 4 - 1, 1);

    // big GEMM (full K, single dispatch) -> linear_out (+lin_b)
    gemm4w_kernel<false><<<dim3(O_ / 128, B_ / 128), 256, 0, stream>>>(
        sae_bf, linw_bf, lin_b, out + BO, nullptr, nullptr, nullptr, B_, O_, F_);

    // GEMM2 -> interaction_out, fused final combine:
    //   out0 = global_bias + linear_out + interaction_out
    gemm4w_kernel<true><<<dim3(O_ / 128, B_ / 128), 256, 0, stream>>>(
        h2_bf, w2_bf, b2, out + 2 * BO, out + BO, gbias, out, B_, O_, D_);
}

// Round 7
// 824.424 us; speedup vs baseline: 1.1275x; 1.1275x over previous
//
#include <hip/hip_runtime.h>

#define B_ 2048
#define F_ 16384
#define D_ 512
#define O_ 4096

typedef __attribute__((ext_vector_type(8))) short bf16x8;
typedef __attribute__((ext_vector_type(4))) float f32x4;

__device__ inline unsigned short f2bf(float f) {
    unsigned u = __float_as_uint(f);
    u += 0x7FFFu + ((u >> 16) & 1u);   // RNE
    return (unsigned short)(u >> 16);
}

__device__ inline void glds16(const void* g, void* l) {
    __builtin_amdgcn_global_load_lds((const __attribute__((address_space(1))) void*)g,
                                     (__attribute__((address_space(3))) void*)l, 16, 0, 0);
}

// ---------------- fp32 -> bf16 bulk convert ----------------
__global__ void cvt_bf16_kernel(const float* __restrict__ s, unsigned short* __restrict__ d, int n4) {
    int stride = gridDim.x * blockDim.x;
    for (int i = blockIdx.x * blockDim.x + threadIdx.x; i < n4; i += stride) {
        float4 v = ((const float4*)s)[i];
        ushort4 o;
        o.x = f2bf(v.x); o.y = f2bf(v.y); o.z = f2bf(v.z); o.w = f2bf(v.w);
        ((ushort4*)d)[i] = o;
    }
}

// ---------------- per-row top-20 (exact, JAX tie-break) + bf16 emit ----------------
// key = (float_bits(v) << 32) | ~idx  : larger key = larger value, tie -> smaller idx.
__global__ __launch_bounds__(256) void topk_kernel(const float* __restrict__ sae,
        float* __restrict__ tv, int* __restrict__ ti, unsigned short* __restrict__ sae_bf) {
    __shared__ unsigned long long keys[256 * 20];  // 40 KB
    __shared__ unsigned long long tmp[128 * 20];   // 20 KB
    int tid = threadIdx.x;
    int row = blockIdx.x;
    const float* p = sae + (size_t)row * F_;
    unsigned short* pb = sae_bf + (size_t)row * F_;

    unsigned long long loc[20];
#pragma unroll
    for (int m = 0; m < 20; ++m) loc[m] = 0ull;

#pragma unroll 2
    for (int it = 0; it < F_ / 256; ++it) {
        int i = tid + (it << 8);
        float v = p[i];
        pb[i] = f2bf(v);
        unsigned long long key =
            ((unsigned long long)__float_as_uint(v) << 32) | (unsigned)(~i);
        if (key > loc[19]) {
            loc[19] = key;
#pragma unroll
            for (int j = 19; j > 0; --j) {       // bubble new key up; static indexing only
                unsigned long long a = loc[j - 1], b = loc[j];
                loc[j - 1] = a > b ? a : b;
                loc[j]     = a > b ? b : a;
            }
        }
    }
#pragma unroll
    for (int m = 0; m < 20; ++m) keys[tid * 20 + m] = loc[m];
    __syncthreads();

    for (int step = 1; step < 256; step <<= 1) {
        if ((tid & (2 * step - 1)) == 0) {
            unsigned long long* a = &keys[tid * 20];
            const unsigned long long* b = &keys[(tid + step) * 20];
            unsigned long long* o = &tmp[(tid >> 1) * 20];
            int i = 0, j = 0;
            for (int m = 0; m < 20; ++m) {
                unsigned long long va = a[i], vb = b[j];
                if (va >= vb) { o[m] = va; ++i; } else { o[m] = vb; ++j; }
            }
            for (int m = 0; m < 20; ++m) a[m] = o[m];
        }
        __syncthreads();
    }
    if (tid < 20) {
        unsigned long long k = keys[tid];
        tv[row * 20 + tid] = __uint_as_float((unsigned)(k >> 32));
        ti[row * 20 + tid] = (int)(~(unsigned)k);
    }
}

// ---------------- bi-interaction pooling from sparse top-k ----------------
__global__ __launch_bounds__(256) void bi_kernel(const int* __restrict__ ti,
        const float* __restrict__ tv, const float* __restrict__ emb, float* __restrict__ bi) {
    __shared__ int   si[20];
    __shared__ float sv[20];
    int tid = threadIdx.x, row = blockIdx.x;
    if (tid < 20) { si[tid] = ti[row * 20 + tid]; sv[tid] = tv[row * 20 + tid]; }
    __syncthreads();
    float s0 = 0.f, q0 = 0.f, s1 = 0.f, q1 = 0.f;
    int d0 = tid, d1 = tid + 256;
#pragma unroll
    for (int k = 0; k < 20; ++k) {
        float v = sv[k];
        const float* e = emb + (size_t)si[k] * D_;
        float e0 = e[d0], e1 = e[d1];
        s0 += v * e0; q0 += v * v * e0 * e0;
        s1 += v * e1; q1 += v * v * e1 * e1;
    }
    bi[(size_t)row * D_ + d0] = 0.5f * (s0 * s0 - q0);
    bi[(size_t)row * D_ + d1] = 0.5f * (s1 * s1 - q1);
}

// ---------------- column mean/var -> scale/shift (training BN) ----------------
__global__ __launch_bounds__(256) void colstats_kernel(const float* __restrict__ X,
        const float* __restrict__ gamma, const float* __restrict__ beta,
        float* __restrict__ scale, float* __restrict__ shift, int M, int N) {
    __shared__ float ss[256], qq[256];
    int col = blockIdx.x, tid = threadIdx.x;
    float s = 0.f, q = 0.f;
    for (int r = tid; r < M; r += 256) {
        float x = X[(size_t)r * N + col];
        s += x; q += x * x;
    }
    ss[tid] = s; qq[tid] = q;
    __syncthreads();
    for (int o = 128; o > 0; o >>= 1) {
        if (tid < o) { ss[tid] += ss[tid + o]; qq[tid] += qq[tid + o]; }
        __syncthreads();
    }
    if (tid == 0) {
        float mean = ss[0] / M;
        float var = qq[0] / M - mean * mean;
        float sc = gamma[col] * rsqrtf(var + 1e-5f);
        scale[col] = sc;
        shift[col] = beta[col] - mean * sc;
    }
}

// ---------------- apply BN (+ optional relu), emit bf16 ----------------
__global__ void bn_apply_kernel(const float* __restrict__ X, const float* __restrict__ scale,
        const float* __restrict__ shift, unsigned short* __restrict__ Y,
        int n4, int colmask4, int relu) {
    int stride = gridDim.x * blockDim.x;
    for (int i = blockIdx.x * blockDim.x + threadIdx.x; i < n4; i += stride) {
        float4 x = ((const float4*)X)[i];
        int c = (i & colmask4) * 4;
        float4 sc = *(const float4*)(scale + c);
        float4 sh = *(const float4*)(shift + c);
        float y0 = x.x * sc.x + sh.x;
        float y1 = x.y * sc.y + sh.y;
        float y2 = x.z * sc.z + sh.z;
        float y3 = x.w * sc.w + sh.w;
        if (relu) {
            y0 = fmaxf(y0, 0.f); y1 = fmaxf(y1, 0.f);
            y2 = fmaxf(y2, 0.f); y3 = fmaxf(y3, 0.f);
        }
        ushort4 o;
        o.x = f2bf(y0); o.y = f2bf(y1); o.z = f2bf(y2); o.w = f2bf(y3);
        ((ushort4*)Y)[i] = o;
    }
}

// ---------------- bf16 GEMM: 8-wave + conflict-free swizzle + counted-vmcnt pipeline ----
// out[M,N] = A[M,K] @ W[N,K]^T + bias[N].  128x128 tile, BK=32, 512 threads = 8 waves
// (2 row-groups x 4 col-groups), per-wave 64x32 output (R4 shape, best measured occupancy).
// LDS swizzle (both-sides, verified R6: conflicts -> 0): physical 16B-chunk =
//   logical ^ ((row>>1)&3); write side pre-swizzles the global source chunk,
//   read side uses chunk = lhi ^ ((l15>>1)&3).
// Depth-2 prefetch, 3 LDS buffers, counted vmcnt (loads stay in flight across barriers).
// XCD swizzle: chunked-contiguous + GROUP_M=8 column-major => each XCD owns an 8x8
//   tile region (A 32MB + B 32MB fits L2 reuse far better than 2 full rows).
// FUSE: additionally write out0 = gb[col] + lin[idx] + (acc+bias).
template <bool FUSE>
__global__ __launch_bounds__(512) void gemm8w_kernel(const unsigned short* __restrict__ A,
        const unsigned short* __restrict__ W, const float* __restrict__ bias,
        float* __restrict__ out, const float* __restrict__ lin,
        const float* __restrict__ gb, float* __restrict__ out0,
        int M, int N, int K) {
    __shared__ short As[3 * 4096];  // 3 buffers x 8 KB
    __shared__ short Bs[3 * 4096];
    int tid = threadIdx.x;
    int lane = tid & 63, w = tid >> 6;      // 8 waves
    int wr = w >> 2, wc = w & 3;            // 2 x 4
    int l15 = lane & 15, lhi = lane >> 4;
    int xk = (l15 >> 1) & 3;                // read-side swizzle key
    int rchunk = (lhi ^ xk) << 3;           // swizzled chunk offset (shorts)

    // XCD-aware swizzle: contiguous chunk per XCD, GROUP_M=8 column-major within.
    // Requires nwg%8==0 and gridDim.y%8==0 (true at all call sites).
    int nwg = gridDim.x * gridDim.y;
    int bid = blockIdx.y * gridDim.x + blockIdx.x;
    int s = (bid & 7) * (nwg >> 3) + (bid >> 3);
    int gsz = gridDim.x << 3;               // 8 rows x full width per group
    int g = s / gsz, r = s % gsz;
    int by = (g << 3) + (r & 7);
    int bx = r >> 3;
    int bm = by * 128, bn = bx * 128;

    int rA = tid >> 2;                      // 0..127 (row of the 128-row tile)
    int kp = tid & 3;                       // logical 16B chunk within the 32-wide k tile
    int kps = kp ^ ((rA >> 1) & 3);         // pre-swizzled source chunk
    const unsigned short* gA = A + (size_t)(bm + rA) * K + kps * 8;
    const unsigned short* gB = W + (size_t)(bn + rA) * K + kps * 8;

    f32x4 acc[4][2];
#pragma unroll
    for (int i = 0; i < 4; ++i)
#pragma unroll
        for (int j = 0; j < 2; ++j) { f32x4 z = {0.f, 0.f, 0.f, 0.f}; acc[i][j] = z; }

    auto STAGE = [&](int t, int buf) {
        int k0 = t << 5;
        glds16(gA + k0, (char*)(As + buf * 4096) + w * 1024);  // lane l at +l*16 (HW rule)
        glds16(gB + k0, (char*)(Bs + buf * 4096) + w * 1024);
    };
    auto COMP = [&](int buf) {
        const short* Ab = As + buf * 4096;
        const short* Bb = Bs + buf * 4096;
        bf16x8 af[4], bv[2];
#pragma unroll
        for (int mi = 0; mi < 4; ++mi)
            af[mi] = *(const bf16x8*)&Ab[(wr * 64 + mi * 16 + l15) * 32 + rchunk];
#pragma unroll
        for (int ni = 0; ni < 2; ++ni)
            bv[ni] = *(const bf16x8*)&Bb[(wc * 32 + ni * 16 + l15) * 32 + rchunk];
#pragma unroll
        for (int mi = 0; mi < 4; ++mi)
#pragma unroll
            for (int ni = 0; ni < 2; ++ni)
                acc[mi][ni] = __builtin_amdgcn_mfma_f32_16x16x32_bf16(af[mi], bv[ni], acc[mi][ni], 0, 0, 0);
    };

    int NT = K >> 5;  // >= 16 at all call sites
    STAGE(0, 0);
    STAGE(1, 1);
    int buf = 0;
    for (int t = 0; t < NT - 2; ++t) {
        int nb = buf + 2; if (nb >= 3) nb -= 3;
        STAGE(t + 2, nb);
        asm volatile("s_waitcnt vmcnt(4)" ::: "memory");   // tile t landed; t+1,t+2 in flight
        __builtin_amdgcn_sched_barrier(0);
        __builtin_amdgcn_s_barrier();
        __builtin_amdgcn_sched_barrier(0);
        COMP(buf);
        asm volatile("s_waitcnt lgkmcnt(0)" ::: "memory"); // my ds_reads landed in regs
        __builtin_amdgcn_sched_barrier(0);
        __builtin_amdgcn_s_barrier();                      // safe to overwrite buf next iter
        __builtin_amdgcn_sched_barrier(0);
        ++buf; if (buf >= 3) buf = 0;
    }
    // t = NT-2: only tile NT-1's loads (2) still in flight after this wait
    asm volatile("s_waitcnt vmcnt(2)" ::: "memory");
    __builtin_amdgcn_sched_barrier(0);
    __builtin_amdgcn_s_barrier();
    __builtin_amdgcn_sched_barrier(0);
    COMP(buf);
    asm volatile("s_waitcnt lgkmcnt(0)" ::: "memory");
    __builtin_amdgcn_sched_barrier(0);
    __builtin_amdgcn_s_barrier();
    __builtin_amdgcn_sched_barrier(0);
    ++buf; if (buf >= 3) buf = 0;
    // t = NT-1: drain
    asm volatile("s_waitcnt vmcnt(0)" ::: "memory");
    __builtin_amdgcn_sched_barrier(0);
    __builtin_amdgcn_s_barrier();
    __builtin_amdgcn_sched_barrier(0);
    COMP(buf);

#pragma unroll
    for (int mi = 0; mi < 4; ++mi)
#pragma unroll
        for (int ni = 0; ni < 2; ++ni) {
            int col = bn + wc * 32 + ni * 16 + l15;
            float bb = bias[col];
            float gbv = FUSE ? gb[col] : 0.f;
            int row0 = bm + wr * 64 + mi * 16 + lhi * 4;
#pragma unroll
            for (int r2 = 0; r2 < 4; ++r2) {
                size_t idx = (size_t)(row0 + r2) * N + col;
                float v = acc[mi][ni][r2] + bb;
                out[idx] = v;
                if (FUSE) out0[idx] = gbv + lin[idx] + v;
            }
        }
}

extern "C" void kernel_launch(void* const* d_in, const int* in_sizes, int n_in,
                              void* d_out, int out_size, void* d_ws, size_t ws_size,
                              hipStream_t stream) {
    const float* sae  = (const float*)d_in[0];
    const float* emb  = (const float*)d_in[1];
    const float* lin_w = (const float*)d_in[2];
    const float* lin_b = (const float*)d_in[3];
    const float* gbias = (const float*)d_in[4];
    const float* bn1g = (const float*)d_in[5];
    const float* bn1b = (const float*)d_in[6];
    const float* w1   = (const float*)d_in[7];
    const float* b1   = (const float*)d_in[8];
    const float* bn2g = (const float*)d_in[9];
    const float* bn2b = (const float*)d_in[10];
    const float* w2   = (const float*)d_in[11];
    const float* b2   = (const float*)d_in[12];
    float* out = (float*)d_out;
    const size_t BO = (size_t)B_ * O_;

    char* ws = (char*)d_ws;
    auto alloc = [&](size_t bytes) -> char* {
        char* p = ws;
        ws += (bytes + 255) & ~(size_t)255;
        return p;
    };
    unsigned short* sae_bf  = (unsigned short*)alloc((size_t)B_ * F_ * 2);  // 64 MB
    unsigned short* linw_bf = (unsigned short*)alloc((size_t)O_ * F_ * 2);  // 128 MB
    unsigned short* w1_bf   = (unsigned short*)alloc((size_t)D_ * D_ * 2);
    unsigned short* w2_bf   = (unsigned short*)alloc((size_t)O_ * D_ * 2);
    unsigned short* a1_bf   = (unsigned short*)alloc((size_t)B_ * D_ * 2);
    unsigned short* h2_bf   = (unsigned short*)alloc((size_t)B_ * D_ * 2);
    float* tv = (float*)alloc((size_t)B_ * 20 * 4);
    int*   ti = (int*)alloc((size_t)B_ * 20 * 4);
    float* bi = (float*)alloc((size_t)B_ * D_ * 4);
    float* h1 = (float*)alloc((size_t)B_ * D_ * 4);
    float* sc1 = (float*)alloc(D_ * 4);
    float* sh1 = (float*)alloc(D_ * 4);
    float* sc2 = (float*)alloc(D_ * 4);
    float* sh2 = (float*)alloc(D_ * 4);

    // weight conversions (independent of data path)
    cvt_bf16_kernel<<<2048, 256, 0, stream>>>(lin_w, linw_bf, (int)((size_t)O_ * F_ / 4));
    cvt_bf16_kernel<<<256, 256, 0, stream>>>(w1, w1_bf, D_ * D_ / 4);
    cvt_bf16_kernel<<<1024, 256, 0, stream>>>(w2, w2_bf, O_ * D_ / 4);

    // top-k + sae bf16 emit
    topk_kernel<<<B_, 256, 0, stream>>>(sae, tv, ti, sae_bf);

    // bi-interaction pooling
    bi_kernel<<<B_, 256, 0, stream>>>(ti, tv, emb, bi);

    // BN1 -> bf16, GEMM1
    colstats_kernel<<<D_, 256, 0, stream>>>(bi, bn1g, bn1b, sc1, sh1, B_, D_);
    bn_apply_kernel<<<1024, 256, 0, stream>>>(bi, sc1, sh1, a1_bf, B_ * D_ / 4, D_ / 4 - 1, 0);
    gemm8w_kernel<false><<<dim3(D_ / 128, B_ / 128), 512, 0, stream>>>(
        a1_bf, w1_bf, b1, h1, nullptr, nullptr, nullptr, B_, D_, D_);

    // BN2 + relu -> bf16
    colstats_kernel<<<D_, 256, 0, stream>>>(h1, bn2g, bn2b, sc2, sh2, B_, D_);
    bn_apply_kernel<<<1024, 256, 0, stream>>>(h1, sc2, sh2, h2_bf, B_ * D_ / 4, D_ / 4 - 1, 1);

    // big GEMM (full K, single dispatch) -> linear_out (+lin_b)
    gemm8w_kernel<false><<<dim3(O_ / 128, B_ / 128), 512, 0, stream>>>(
        sae_bf, linw_bf, lin_b, out + BO, nullptr, nullptr, nullptr, B_, O_, F_);

    // GEMM2 -> interaction_out, fused final combine:
    //   out0 = global_bias + linear_out + interaction_out
    gemm8w_kernel<true><<<dim3(O_ / 128, B_ / 128), 512, 0, stream>>>(
        h2_bf, w2_bf, b2, out + 2 * BO, out + BO, gbias, out, B_, O_, D_);
}

// Round 8
// 760.915 us; speedup vs baseline: 1.2216x; 1.0835x over previous
//
#include <hip/hip_runtime.h>

#define B_ 2048
#define F_ 16384
#define D_ 512
#define O_ 4096

typedef __attribute__((ext_vector_type(8))) short bf16x8;
typedef __attribute__((ext_vector_type(4))) float f32x4;

__device__ inline unsigned short f2bf(float f) {
    unsigned u = __float_as_uint(f);
    u += 0x7FFFu + ((u >> 16) & 1u);   // RNE
    return (unsigned short)(u >> 16);
}

__device__ inline void glds16(const void* g, void* l) {
    __builtin_amdgcn_global_load_lds((const __attribute__((address_space(1))) void*)g,
                                     (__attribute__((address_space(3))) void*)l, 16, 0, 0);
}

// ---------------- fp32 -> bf16 bulk convert ----------------
__global__ void cvt_bf16_kernel(const float* __restrict__ s, unsigned short* __restrict__ d, int n4) {
    int stride = gridDim.x * blockDim.x;
    for (int i = blockIdx.x * blockDim.x + threadIdx.x; i < n4; i += stride) {
        float4 v = ((const float4*)s)[i];
        ushort4 o;
        o.x = f2bf(v.x); o.y = f2bf(v.y); o.z = f2bf(v.z); o.w = f2bf(v.w);
        ((ushort4*)d)[i] = o;
    }
}

// ---------------- per-row top-20 (exact, JAX tie-break) + bf16 emit ----------------
// key = (float_bits(v) << 32) | ~idx  : larger key = larger value, tie -> smaller idx.
__global__ __launch_bounds__(256) void topk_kernel(const float* __restrict__ sae,
        float* __restrict__ tv, int* __restrict__ ti, unsigned short* __restrict__ sae_bf) {
    __shared__ unsigned long long keys[256 * 20];  // 40 KB
    __shared__ unsigned long long tmp[128 * 20];   // 20 KB
    int tid = threadIdx.x;
    int row = blockIdx.x;
    const float* p = sae + (size_t)row * F_;
    unsigned short* pb = sae_bf + (size_t)row * F_;

    unsigned long long loc[20];
#pragma unroll
    for (int m = 0; m < 20; ++m) loc[m] = 0ull;

#pragma unroll 2
    for (int it = 0; it < F_ / 256; ++it) {
        int i = tid + (it << 8);
        float v = p[i];
        pb[i] = f2bf(v);
        unsigned long long key =
            ((unsigned long long)__float_as_uint(v) << 32) | (unsigned)(~i);
        if (key > loc[19]) {
            loc[19] = key;
#pragma unroll
            for (int j = 19; j > 0; --j) {       // bubble new key up; static indexing only
                unsigned long long a = loc[j - 1], b = loc[j];
                loc[j - 1] = a > b ? a : b;
                loc[j]     = a > b ? b : a;
            }
        }
    }
#pragma unroll
    for (int m = 0; m < 20; ++m) keys[tid * 20 + m] = loc[m];
    __syncthreads();

    for (int step = 1; step < 256; step <<= 1) {
        if ((tid & (2 * step - 1)) == 0) {
            unsigned long long* a = &keys[tid * 20];
            const unsigned long long* b = &keys[(tid + step) * 20];
            unsigned long long* o = &tmp[(tid >> 1) * 20];
            int i = 0, j = 0;
            for (int m = 0; m < 20; ++m) {
                unsigned long long va = a[i], vb = b[j];
                if (va >= vb) { o[m] = va; ++i; } else { o[m] = vb; ++j; }
            }
            for (int m = 0; m < 20; ++m) a[m] = o[m];
        }
        __syncthreads();
    }
    if (tid < 20) {
        unsigned long long k = keys[tid];
        tv[row * 20 + tid] = __uint_as_float((unsigned)(k >> 32));
        ti[row * 20 + tid] = (int)(~(unsigned)k);
    }
}

// ---------------- bi-interaction pooling from sparse top-k ----------------
__global__ __launch_bounds__(256) void bi_kernel(const int* __restrict__ ti,
        const float* __restrict__ tv, const float* __restrict__ emb, float* __restrict__ bi) {
    __shared__ int   si[20];
    __shared__ float sv[20];
    int tid = threadIdx.x, row = blockIdx.x;
    if (tid < 20) { si[tid] = ti[row * 20 + tid]; sv[tid] = tv[row * 20 + tid]; }
    __syncthreads();
    float s0 = 0.f, q0 = 0.f, s1 = 0.f, q1 = 0.f;
    int d0 = tid, d1 = tid + 256;
#pragma unroll
    for (int k = 0; k < 20; ++k) {
        float v = sv[k];
        const float* e = emb + (size_t)si[k] * D_;
        float e0 = e[d0], e1 = e[d1];
        s0 += v * e0; q0 += v * v * e0 * e0;
        s1 += v * e1; q1 += v * v * e1 * e1;
    }
    bi[(size_t)row * D_ + d0] = 0.5f * (s0 * s0 - q0);
    bi[(size_t)row * D_ + d1] = 0.5f * (s1 * s1 - q1);
}

// ---------------- column mean/var -> scale/shift (training BN) ----------------
__global__ __launch_bounds__(256) void colstats_kernel(const float* __restrict__ X,
        const float* __restrict__ gamma, const float* __restrict__ beta,
        float* __restrict__ scale, float* __restrict__ shift, int M, int N) {
    __shared__ float ss[256], qq[256];
    int col = blockIdx.x, tid = threadIdx.x;
    float s = 0.f, q = 0.f;
    for (int r = tid; r < M; r += 256) {
        float x = X[(size_t)r * N + col];
        s += x; q += x * x;
    }
    ss[tid] = s; qq[tid] = q;
    __syncthreads();
    for (int o = 128; o > 0; o >>= 1) {
        if (tid < o) { ss[tid] += ss[tid + o]; qq[tid] += qq[tid + o]; }
        __syncthreads();
    }
    if (tid == 0) {
        float mean = ss[0] / M;
        float var = qq[0] / M - mean * mean;
        float sc = gamma[col] * rsqrtf(var + 1e-5f);
        scale[col] = sc;
        shift[col] = beta[col] - mean * sc;
    }
}

// ---------------- apply BN (+ optional relu), emit bf16 ----------------
__global__ void bn_apply_kernel(const float* __restrict__ X, const float* __restrict__ scale,
        const float* __restrict__ shift, unsigned short* __restrict__ Y,
        int n4, int colmask4, int relu) {
    int stride = gridDim.x * blockDim.x;
    for (int i = blockIdx.x * blockDim.x + threadIdx.x; i < n4; i += stride) {
        float4 x = ((const float4*)X)[i];
        int c = (i & colmask4) * 4;
        float4 sc = *(const float4*)(scale + c);
        float4 sh = *(const float4*)(shift + c);
        float y0 = x.x * sc.x + sh.x;
        float y1 = x.y * sc.y + sh.y;
        float y2 = x.z * sc.z + sh.z;
        float y3 = x.w * sc.w + sh.w;
        if (relu) {
            y0 = fmaxf(y0, 0.f); y1 = fmaxf(y1, 0.f);
            y2 = fmaxf(y2, 0.f); y3 = fmaxf(y3, 0.f);
        }
        ushort4 o;
        o.x = f2bf(y0); o.y = f2bf(y1); o.z = f2bf(y2); o.w = f2bf(y3);
        ((ushort4*)Y)[i] = o;
    }
}

// ---------------- bf16 GEMM: 8-wave, swizzled LDS, frag-double-buffered pipeline ----
// out[M,N] = A[M,K] @ W[N,K]^T + bias[N].  128x128 tile, BK=32, 512 threads = 8 waves
// (2 row-groups x 4 col-groups), per-wave 64x32 output.
// Phase overlap (the R7 fix): each sub-step issues NEXT tile's 6 ds_reads right after
// the barrier, then runs CURRENT tile's 8 MFMAs while they're in flight; lgkmcnt(0)
// sits just before the next barrier. One barrier per K-step; vmcnt(2) counted (never
// drained mid-loop).  Race-free: reads of a buffer complete (lgkmcnt0) before the
// barrier that precedes any wave's re-STAGE of that buffer.
// LDS swizzle (both-sides, verified: conflicts==0): chunk = logical ^ ((row>>1)&3).
// XCD swizzle: contiguous chunk per XCD + GROUP_M=8 column-major (verified FETCH drop).
// FUSE: additionally write out0 = gb[col] + lin[idx] + (acc+bias).
template <bool FUSE>
__global__ __launch_bounds__(512) void gemm8w_kernel(const unsigned short* __restrict__ A,
        const unsigned short* __restrict__ W, const float* __restrict__ bias,
        float* __restrict__ out, const float* __restrict__ lin,
        const float* __restrict__ gb, float* __restrict__ out0,
        int M, int N, int K) {
    __shared__ short As[3 * 4096];  // 3 buffers x 8 KB
    __shared__ short Bs[3 * 4096];
    int tid = threadIdx.x;
    int lane = tid & 63, w = tid >> 6;      // 8 waves
    int wr = w >> 2, wc = w & 3;            // 2 x 4
    int l15 = lane & 15, lhi = lane >> 4;
    int xk = (l15 >> 1) & 3;                // read-side swizzle key
    int rchunk = (lhi ^ xk) << 3;           // swizzled chunk offset (shorts)

    // XCD-aware swizzle: contiguous chunk per XCD, GROUP_M=8 column-major within.
    int nwg = gridDim.x * gridDim.y;
    int bid = blockIdx.y * gridDim.x + blockIdx.x;
    int s = (bid & 7) * (nwg >> 3) + (bid >> 3);
    int gsz = gridDim.x << 3;
    int g = s / gsz, r = s % gsz;
    int by = (g << 3) + (r & 7);
    int bx = r >> 3;
    int bm = by * 128, bn = bx * 128;

    int rA = tid >> 2;                      // 0..127 (row of the 128-row tile)
    int kp = tid & 3;                       // logical 16B chunk within the 32-wide k tile
    int kps = kp ^ ((rA >> 1) & 3);         // pre-swizzled source chunk
    const unsigned short* gA = A + (size_t)(bm + rA) * K + kps * 8;
    const unsigned short* gB = W + (size_t)(bn + rA) * K + kps * 8;

    f32x4 acc[4][2];
#pragma unroll
    for (int i = 0; i < 4; ++i)
#pragma unroll
        for (int j = 0; j < 2; ++j) { f32x4 z = {0.f, 0.f, 0.f, 0.f}; acc[i][j] = z; }

    auto STAGE = [&](int t, int buf) {
        int k0 = t << 5;
        glds16(gA + k0, (char*)(As + buf * 4096) + w * 1024);  // lane l at +l*16 (HW rule)
        glds16(gB + k0, (char*)(Bs + buf * 4096) + w * 1024);
    };
    auto LOADF = [&](bf16x8* af, bf16x8* bv, int buf) {
        const short* Ab = As + buf * 4096;
        const short* Bb = Bs + buf * 4096;
#pragma unroll
        for (int mi = 0; mi < 4; ++mi)
            af[mi] = *(const bf16x8*)&Ab[(wr * 64 + mi * 16 + l15) * 32 + rchunk];
#pragma unroll
        for (int ni = 0; ni < 2; ++ni)
            bv[ni] = *(const bf16x8*)&Bb[(wc * 32 + ni * 16 + l15) * 32 + rchunk];
    };
    auto MFMA8 = [&](const bf16x8* af, const bf16x8* bv) {
#pragma unroll
        for (int mi = 0; mi < 4; ++mi)
#pragma unroll
            for (int ni = 0; ni < 2; ++ni)
                acc[mi][ni] = __builtin_amdgcn_mfma_f32_16x16x32_bf16(af[mi], bv[ni], acc[mi][ni], 0, 0, 0);
    };

    int NT = K >> 5;  // even, >= 16 at all call sites

    STAGE(0, 0);
    STAGE(1, 1);
    asm volatile("s_waitcnt vmcnt(2)" ::: "memory");   // tile 0 staged (mine)
    __builtin_amdgcn_sched_barrier(0);
    __builtin_amdgcn_s_barrier();                      // all waves staged tile 0
    __builtin_amdgcn_sched_barrier(0);

    bf16x8 afA[4], bvA[2], afB[4], bvB[2];
    LOADF(afA, bvA, 0);                                // frags for tile 0 in flight

    for (int t = 0; t + 4 <= NT; t += 2) {
        // ---- even sub-step: MFMA tile t (fA), prefetch frags t+1 (fB) ----
        STAGE(t + 2, (t + 2) % 3);
        asm volatile("s_waitcnt lgkmcnt(0)" ::: "memory");   // fA landed
        __builtin_amdgcn_sched_barrier(0);
        asm volatile("s_waitcnt vmcnt(2)" ::: "memory");     // tile t+1 staged (mine)
        __builtin_amdgcn_sched_barrier(0);
        __builtin_amdgcn_s_barrier();                        // all waves: t+1 ready, t-1 reads done
        __builtin_amdgcn_sched_barrier(0);
        LOADF(afB, bvB, (t + 1) % 3);
        __builtin_amdgcn_s_setprio(1);
        MFMA8(afA, bvA);
        __builtin_amdgcn_s_setprio(0);
        __builtin_amdgcn_sched_group_barrier(0x100, 6, 0);   // 6 ds_read issue first
        __builtin_amdgcn_sched_group_barrier(0x008, 8, 0);   // then 8 MFMA
        // ---- odd sub-step: MFMA tile t+1 (fB), prefetch frags t+2 (fA) ----
        STAGE(t + 3, (t + 3) % 3);
        asm volatile("s_waitcnt lgkmcnt(0)" ::: "memory");   // fB landed
        __builtin_amdgcn_sched_barrier(0);
        asm volatile("s_waitcnt vmcnt(2)" ::: "memory");     // tile t+2 staged (mine)
        __builtin_amdgcn_sched_barrier(0);
        __builtin_amdgcn_s_barrier();
        __builtin_amdgcn_sched_barrier(0);
        LOADF(afA, bvA, (t + 2) % 3);
        __builtin_amdgcn_s_setprio(1);
        MFMA8(afB, bvB);
        __builtin_amdgcn_s_setprio(0);
        __builtin_amdgcn_sched_group_barrier(0x100, 6, 0);
        __builtin_amdgcn_sched_group_barrier(0x008, 8, 0);
    }
    // ---- peel: tiles NT-2 (fA) and NT-1 ----
    asm volatile("s_waitcnt lgkmcnt(0)" ::: "memory");       // fA landed
    __builtin_amdgcn_sched_barrier(0);
    asm volatile("s_waitcnt vmcnt(0)" ::: "memory");         // tile NT-1 staged (mine)
    __builtin_amdgcn_sched_barrier(0);
    __builtin_amdgcn_s_barrier();
    __builtin_amdgcn_sched_barrier(0);
    LOADF(afB, bvB, (NT - 1) % 3);
    __builtin_amdgcn_s_setprio(1);
    MFMA8(afA, bvA);
    __builtin_amdgcn_s_setprio(0);
    asm volatile("s_waitcnt lgkmcnt(0)" ::: "memory");       // fB landed
    __builtin_amdgcn_sched_barrier(0);
    __builtin_amdgcn_s_setprio(1);
    MFMA8(afB, bvB);
    __builtin_amdgcn_s_setprio(0);

#pragma unroll
    for (int mi = 0; mi < 4; ++mi)
#pragma unroll
        for (int ni = 0; ni < 2; ++ni) {
            int col = bn + wc * 32 + ni * 16 + l15;
            float bb = bias[col];
            float gbv = FUSE ? gb[col] : 0.f;
            int row0 = bm + wr * 64 + mi * 16 + lhi * 4;
#pragma unroll
            for (int r2 = 0; r2 < 4; ++r2) {
                size_t idx = (size_t)(row0 + r2) * N + col;
                float v = acc[mi][ni][r2] + bb;
                out[idx] = v;
                if (FUSE) out0[idx] = gbv + lin[idx] + v;
            }
        }
}

extern "C" void kernel_launch(void* const* d_in, const int* in_sizes, int n_in,
                              void* d_out, int out_size, void* d_ws, size_t ws_size,
                              hipStream_t stream) {
    const float* sae  = (const float*)d_in[0];
    const float* emb  = (const float*)d_in[1];
    const float* lin_w = (const float*)d_in[2];
    const float* lin_b = (const float*)d_in[3];
    const float* gbias = (const float*)d_in[4];
    const float* bn1g = (const float*)d_in[5];
    const float* bn1b = (const float*)d_in[6];
    const float* w1   = (const float*)d_in[7];
    const float* b1   = (const float*)d_in[8];
    const float* bn2g = (const float*)d_in[9];
    const float* bn2b = (const float*)d_in[10];
    const float* w2   = (const float*)d_in[11];
    const float* b2   = (const float*)d_in[12];
    float* out = (float*)d_out;
    const size_t BO = (size_t)B_ * O_;

    char* ws = (char*)d_ws;
    auto alloc = [&](size_t bytes) -> char* {
        char* p = ws;
        ws += (bytes + 255) & ~(size_t)255;
        return p;
    };
    unsigned short* sae_bf  = (unsigned short*)alloc((size_t)B_ * F_ * 2);  // 64 MB
    unsigned short* linw_bf = (unsigned short*)alloc((size_t)O_ * F_ * 2);  // 128 MB
    unsigned short* w1_bf   = (unsigned short*)alloc((size_t)D_ * D_ * 2);
    unsigned short* w2_bf   = (unsigned short*)alloc((size_t)O_ * D_ * 2);
    unsigned short* a1_bf   = (unsigned short*)alloc((size_t)B_ * D_ * 2);
    unsigned short* h2_bf   = (unsigned short*)alloc((size_t)B_ * D_ * 2);
    float* tv = (float*)alloc((size_t)B_ * 20 * 4);
    int*   ti = (int*)alloc((size_t)B_ * 20 * 4);
    float* bi = (float*)alloc((size_t)B_ * D_ * 4);
    float* h1 = (float*)alloc((size_t)B_ * D_ * 4);
    float* sc1 = (float*)alloc(D_ * 4);
    float* sh1 = (float*)alloc(D_ * 4);
    float* sc2 = (float*)alloc(D_ * 4);
    float* sh2 = (float*)alloc(D_ * 4);

    // weight conversions (independent of data path)
    cvt_bf16_kernel<<<2048, 256, 0, stream>>>(lin_w, linw_bf, (int)((size_t)O_ * F_ / 4));
    cvt_bf16_kernel<<<256, 256, 0, stream>>>(w1, w1_bf, D_ * D_ / 4);
    cvt_bf16_kernel<<<1024, 256, 0, stream>>>(w2, w2_bf, O_ * D_ / 4);

    // top-k + sae bf16 emit
    topk_kernel<<<B_, 256, 0, stream>>>(sae, tv, ti, sae_bf);

    // bi-interaction pooling
    bi_kernel<<<B_, 256, 0, stream>>>(ti, tv, emb, bi);

    // BN1 -> bf16, GEMM1
    colstats_kernel<<<D_, 256, 0, stream>>>(bi, bn1g, bn1b, sc1, sh1, B_, D_);
    bn_apply_kernel<<<1024, 256, 0, stream>>>(bi, sc1, sh1, a1_bf, B_ * D_ / 4, D_ / 4 - 1, 0);
    gemm8w_kernel<false><<<dim3(D_ / 128, B_ / 128), 512, 0, stream>>>(
        a1_bf, w1_bf, b1, h1, nullptr, nullptr, nullptr, B_, D_, D_);

    // BN2 + relu -> bf16
    colstats_kernel<<<D_, 256, 0, stream>>>(h1, bn2g, bn2b, sc2, sh2, B_, D_);
    bn_apply_kernel<<<1024, 256, 0, stream>>>(h1, sc2, sh2, h2_bf, B_ * D_ / 4, D_ / 4 - 1, 1);

    // big GEMM (full K, single dispatch) -> linear_out (+lin_b)
    gemm8w_kernel<false><<<dim3(O_ / 128, B_ / 128), 512, 0, stream>>>(
        sae_bf, linw_bf, lin_b, out + BO, nullptr, nullptr, nullptr, B_, O_, F_);

    // GEMM2 -> interaction_out, fused final combine:
    //   out0 = global_bias + linear_out + interaction_out
    gemm8w_kernel<true><<<dim3(O_ / 128, B_ / 128), 512, 0, stream>>>(
        h2_bf, w2_bf, b2, out + 2 * BO, out + BO, gbias, out, B_, O_, D_);
}